// Round 5
// baseline (82.524 us; speedup 1.0000x reference)
//
#include <hip/hip_runtime.h>
#include <math.h>

#define BB 64          // batch
#define CC 16          // children per sample
#define DD 512         // feature dim
#define LL 8192        // CC*DD flattened length
#define EPSV 1e-8f
#define INVT 10.0f     // 1/TEMPERATURE
#define NEGINF_T (-1e31f)   // NEG_INF / TEMPERATURE

// ws layout (floats):
//  [0,     1024)  n2i : ||ci row r||^2   (r = b*16+c)
//  [1024,  2048)  n2j : ||cj row r||^2
//  [2048,  6144)  dj  : raw gathered dots vs cj  [64,64]
//  [6144, 10240)  dk  : raw gathered dots vs ci  [64,64]
//  [10240,10304)  pos : dot(fi, fj) per anchor
#define WS_N2I 0
#define WS_N2J 1024
#define WS_DJ  2048
#define WS_DK  6144
#define WS_POS 10240

__device__ __forceinline__ float dot4(float4 a, float4 b) {
    return a.x * b.x + a.y * b.y + a.z * b.z + a.w * b.w;
}

__device__ __forceinline__ float wave_reduce(float v) {
    #pragma unroll
    for (int off = 32; off; off >>= 1) v += __shfl_down(v, off);
    return v;
}

// ---------------------------------------------------------------------------
// main — LDS-staged gather (traffic-cut restructure; r3/r4 showed sim is
// per-CU global-path-BW-bound at ~290MB, not occupancy/latency-bound):
//   512 blocks: side=b&1 (0: rows from cj / idx nj / out dj;
//                         1: rows from ci / idx nk / out dk),
//               jg=(b>>1)&31 (j pair {2jg,2jg+1}), ig=b>>6 (anchors 8ig..8ig+7).
//   Block stages its 2 j's x 16 rows (64KB) in LDS ONCE; all 8 anchors'
//   gathers are served from LDS. Global traffic: 32MB stage + 131MB fi
//   (was 256MB gathers + 32MB fi). 66KB LDS -> 2 blocks/CU.
//   Folded roles (no extra blocks):
//     - norms: ig==0 blocks self-dot their staged rows.
//     - pos:   side==0 blocks with ig==jg>>2 also dot fi against the
//              identity-indexed staged rows (i == 2jg+jj diagonal).
//   b==0 zeroes out[0] (final kernel atomically accumulates; dispatch
//   boundary orders it).
// ---------------------------------------------------------------------------
__global__ __launch_bounds__(256) void ntx_main(const float* __restrict__ ci,
                                                const float* __restrict__ cj,
                                                const int* __restrict__ nj,
                                                const int* __restrict__ nk,
                                                float* __restrict__ ws,
                                                float* __restrict__ out) {
    __shared__ float4 rows4[4096];       // 64KB: 32 rows x 512 floats
    __shared__ int    sidx[8][32];       // [anchor][jj*16+c]
    __shared__ float  red[8][2][4];      // [anchor][jj][wave]
    __shared__ float  pred[2][4];        // pos partials [jj][wave]

    const int b = blockIdx.x, tid = threadIdx.x;
    const int side  = b & 1;
    const int jg    = (b >> 1) & 31;
    const int ig    = b >> 6;
    const int ibase = ig * 8;

    if (b == 0 && tid == 0) out[0] = 0.f;

    // stage 2 j's x 16 rows (contiguous 64KB) into LDS
    const float4* rsrc = (const float4*)(side ? ci : cj) + jg * 4096;
    #pragma unroll
    for (int k = 0; k < 16; ++k) rows4[tid + 256 * k] = rsrc[tid + 256 * k];

    // stage gather indices for this block's 8 anchors x 2 j's x 16 c's
    const int* nsrc = side ? nk : nj;
    sidx[tid >> 5][tid & 31] = nsrc[(ibase + (tid >> 5)) * 1024 + jg * 32 + (tid & 31)];

    __syncthreads();

    // norms role: ig==0 blocks self-dot the staged rows (32 rows, 8 thr/row)
    if (ig == 0) {
        const int row = tid >> 3, seg = tid & 7;
        float acc = 0.f;
        #pragma unroll
        for (int k = 0; k < 16; ++k) {
            float4 v = rows4[row * 128 + seg * 16 + k];
            acc += dot4(v, v);
        }
        acc += __shfl_down(acc, 4);
        acc += __shfl_down(acc, 2);
        acc += __shfl_down(acc, 1);
        if (seg == 0) ws[(side ? WS_N2I : WS_N2J) + jg * 32 + row] = acc;
    }

    const int d4   = tid & 127;          // float4 offset within a row
    const int half = tid >> 7;           // c parity handled by this half
    const int wave = tid >> 6;
    const bool diagblk = (side == 0) && (ig == (jg >> 2));

    const float4* cib = (const float4*)ci;
    for (int ip = 0; ip < 8; ++ip) {
        const int i = ibase + ip;
        const float4* fi4 = cib + i * 2048;
        float4 fiv[8];
        #pragma unroll
        for (int it = 0; it < 8; ++it) fiv[it] = fi4[tid + 256 * it];

        #pragma unroll
        for (int jj = 0; jj < 2; ++jj) {
            const bool dodiag = diagblk && (i == 2 * jg + jj);
            float a = 0.f, ap = 0.f;
            #pragma unroll
            for (int it = 0; it < 8; ++it) {
                const int c  = half + 2 * it;
                const int rr = sidx[ip][jj * 16 + c];
                a += dot4(fiv[it], rows4[(jj * 16 + rr) * 128 + d4]);
                if (dodiag) ap += dot4(fiv[it], rows4[(jj * 16 + c) * 128 + d4]);
            }
            a = wave_reduce(a);
            if ((tid & 63) == 0) red[ip][jj][wave] = a;
            if (dodiag) {
                ap = wave_reduce(ap);
                if ((tid & 63) == 0) pred[jj][wave] = ap;
            }
        }
    }
    __syncthreads();
    if (tid < 16) {
        const int ip = tid >> 1, jj = tid & 1;
        float s = red[ip][jj][0] + red[ip][jj][1] + red[ip][jj][2] + red[ip][jj][3];
        ws[(side ? WS_DK : WS_DJ) + (ibase + ip) * BB + 2 * jg + jj] = s;
    }
    if (diagblk && tid < 2) {
        float p = pred[tid][0] + pred[tid][1] + pred[tid][2] + pred[tid][3];
        ws[WS_POS + 2 * jg + tid] = p;
    }
}

// ---------------------------------------------------------------------------
// final: block i, lane j. Normalize raw dots, masked logsumexp over 129
// logits via wave butterfly, atomicAdd loss_i/(2B) into out.
// ---------------------------------------------------------------------------
__global__ __launch_bounds__(64) void ntx_final(const int* __restrict__ pids,
                                                const int* __restrict__ nj,
                                                const int* __restrict__ nk,
                                                const float* __restrict__ ws,
                                                float* __restrict__ out) {
    const int i = blockIdx.x, j = threadIdx.x;
    __shared__ float sn2i[1024], sn2j[1024];
    const float4* n2i4 = (const float4*)(ws + WS_N2I);
    const float4* n2j4 = (const float4*)(ws + WS_N2J);
    #pragma unroll
    for (int t = 0; t < 4; ++t) {
        ((float4*)sn2i)[j + 64 * t] = n2i4[j + 64 * t];
        ((float4*)sn2j)[j + 64 * t] = n2j4[j + 64 * t];
    }
    __syncthreads();

    float si = 0.f, sjf = 0.f;
    #pragma unroll
    for (int c = 0; c < CC; ++c) { si += sn2i[i * CC + c]; sjf += sn2j[i * CC + c]; }
    const float ni = fmaxf(sqrtf(si), EPSV);
    const float l0 = ws[WS_POS + i] / (ni * fmaxf(sqrtf(sjf), EPSV)) * INVT;

    const int4* nj4 = (const int4*)(nj + (i * BB + j) * CC);
    const int4* nk4 = (const int4*)(nk + (i * BB + j) * CC);
    float gj = 0.f, gk = 0.f;
    #pragma unroll
    for (int t = 0; t < 4; ++t) {
        int4 a = nj4[t];
        gj += sn2j[j * CC + a.x] + sn2j[j * CC + a.y] + sn2j[j * CC + a.z] + sn2j[j * CC + a.w];
        int4 bq = nk4[t];
        gk += sn2i[j * CC + bq.x] + sn2i[j * CC + bq.y] + sn2i[j * CC + bq.z] + sn2i[j * CC + bq.w];
    }

    const bool valid = (j != i) && (pids[j] != pids[i]);
    float lj = NEGINF_T, lk = NEGINF_T;
    if (valid) {
        const float inv = INVT / ni;
        lj = ws[WS_DJ + i * BB + j] / fmaxf(sqrtf(gj), EPSV) * inv;
        lk = ws[WS_DK + i * BB + j] / fmaxf(sqrtf(gk), EPSV) * inv;
    }

    float m = fmaxf(lj, lk);
    #pragma unroll
    for (int off = 32; off; off >>= 1) m = fmaxf(m, __shfl_xor(m, off));
    m = fmaxf(m, l0);

    float s = __expf(lj - m) + __expf(lk - m);
    s = wave_reduce(s);
    if (j == 0) {
        s += __expf(l0 - m);
        const float loss_i = -l0 + m + __logf(s);
        atomicAdd(out, loss_i * (1.0f / (2.0f * BB)));
    }
}

// ---------------------------------------------------------------------------
extern "C" void kernel_launch(void* const* d_in, const int* in_sizes, int n_in,
                              void* d_out, int out_size, void* d_ws, size_t ws_size,
                              hipStream_t stream) {
    const float* ci  = (const float*)d_in[0];
    const float* cj  = (const float*)d_in[1];
    const int*  pids = (const int*) d_in[2];
    const int*  nj   = (const int*) d_in[3];
    const int*  nk   = (const int*) d_in[4];
    float* ws  = (float*)d_ws;
    float* out = (float*)d_out;

    ntx_main<<<512, 256, 0, stream>>>(ci, cj, nj, nk, ws, out);
    ntx_final<<<BB, 64, 0, stream>>>(pids, nj, nk, ws, out);
}